// Round 5
// baseline (17505.638 us; speedup 1.0000x reference)
//
#include <hip/hip_runtime.h>
#include <hip/hip_bf16.h>
#include <stdint.h>

// LSTM: B=64, T=2048, I=256, H=512, O=10 (fp32 in/out)
// v3 = v2 + PING-PONG h buffers (fixes v2's livelock: single-buffer + exact-tag
// let a +1-step producer permanently overwrite a cell a slow consumer still
// needed). Tag t lives in buffer t&1; overwrite of tag-t cells (by tag t+2)
// requires ALL WGs to have published t+1, i.e. all step-t reads are done.
//
//  - 128 WGs x 512 threads. 4 groups x 32 WGs; group g owns batches [16g,16g+16).
//  - WG w in group owns h-cols [16w,16w+16) => gate rows {q*512 + 16w + c}.
//  - Wave wv (8/WG) owns K-slice [64wv,64wv+64) of H and I-slice [32wv,+32) of I.
//  - W_hh in registers as bf16 hi/lo split MFMA A-frags (3-term fp32-accurate);
//    W_ih single bf16. x prefetched; ih-MFMA hoisted before the poll.
//  - h word = u64 {hi32: tag, lo32: bf16hi|bf16lo}. Exact-tag match before use;
//    0xAA poison never matches; tags monotonic; replay-safe.
//  - head_fc reads final h (tag 2048, buffer 0) straight from the tagged buffer.

#define T_SEQ 2048
#define NB    64
#define IDIM  256
#define HDIM  512
#define NGRP  4
#define BG    16
#define WPG   32
#define NWG   128
#define NTHR  512
#define ODIM  10
#define HBUF  (NGRP * BG * HDIM)   // u64 cells per ping-pong buffer (32768)

typedef float  f32x4  __attribute__((ext_vector_type(4)));
typedef short  short8 __attribute__((ext_vector_type(8)));
typedef float  fl4    __attribute__((ext_vector_type(4)));
typedef unsigned long long ull;

union Frag { uint32_t u[4]; short8 v; };

__device__ inline unsigned short f2bf(float f) {
  unsigned int u = __float_as_uint(f);
  u += 0x7FFFu + ((u >> 16) & 1u);          // RNE
  return (unsigned short)(u >> 16);
}
__device__ inline float bf2f(unsigned short s) {
  return __uint_as_float(((unsigned int)s) << 16);
}
__device__ inline float sigm(float x)  { return 1.0f / (1.0f + __expf(-x)); }
__device__ inline float tanh_(float x) { float e = __expf(2.0f * x); return 1.0f - 2.0f / (e + 1.0f); }

__device__ inline ull ld_agent(const ull* p) {
  return __hip_atomic_load(p, __ATOMIC_RELAXED, __HIP_MEMORY_SCOPE_AGENT);
}
__device__ inline void st_agent(ull* p, ull v) {
  __hip_atomic_store(p, v, __ATOMIC_RELAXED, __HIP_MEMORY_SCOPE_AGENT);
}

__global__ __launch_bounds__(NTHR, 2)
void lstm_persist(const float* __restrict__ x,
                  const float* __restrict__ W_ih,
                  const float* __restrict__ W_hh,
                  const float* __restrict__ b_ih,
                  const float* __restrict__ b_hh,
                  ull* __restrict__ hq)            // [2][grp][16b][512c] tagged u64
{
  __shared__ float ldsC[2][8][4][16][20];  // [buf][wave][gate q][batch][c+pad]

  const int bid = blockIdx.x;
  const int g   = bid & 3;           // group
  const int w   = bid >> 2;          // 0..31 within group
  const int tid = threadIdx.x;
  const int wv  = tid >> 6;          // wave 0..7
  const int l   = tid & 63;
  const int l16 = l & 15;
  const int lk  = l >> 4;            // 0..3

  // ---- one-time: W_hh fragments (bf16 hi/lo split) + W_ih fragments ----
  Frag whi[4][2], wlo[4][2], wih[4];
  #pragma unroll
  for (int q = 0; q < 4; ++q) {
    const int row = q * HDIM + w * 16 + l16;            // gate row in [0,2048)
    #pragma unroll
    for (int kt = 0; kt < 2; ++kt) {
      const float* p = W_hh + (size_t)row * HDIM + wv * 64 + kt * 32 + lk * 8;
      #pragma unroll
      for (int pj = 0; pj < 4; ++pj) {
        float a = p[2 * pj], b2 = p[2 * pj + 1];
        unsigned short ha = f2bf(a), hb = f2bf(b2);
        unsigned short la = f2bf(a - bf2f(ha)), lb = f2bf(b2 - bf2f(hb));
        whi[q][kt].u[pj] = (uint32_t)ha | ((uint32_t)hb << 16);
        wlo[q][kt].u[pj] = (uint32_t)la | ((uint32_t)lb << 16);
      }
    }
    const float* pi = W_ih + (size_t)row * IDIM + wv * 32 + lk * 8;
    #pragma unroll
    for (int pj = 0; pj < 4; ++pj)
      wih[q].u[pj] = (uint32_t)f2bf(pi[2 * pj]) | ((uint32_t)f2bf(pi[2 * pj + 1]) << 16);
  }

  // ---- update-role (tid<256): one (c,b) cell each; c-state in a register ----
  const int ub = tid & 15;           // batch within group
  const int uc = tid >> 4;           // col-local 0..15 (valid for tid<256)
  float bias[4];
  float cstate = 0.0f;
  if (tid < 256) {
    #pragma unroll
    for (int q = 0; q < 4; ++q) {
      int row = q * HDIM + w * 16 + uc;
      bias[q] = b_ih[row] + b_hh[row];
    }
  }

  const size_t xbase = ((size_t)(g * BG + l16) * T_SEQ) * IDIM + wv * 32 + lk * 8;
  const ull* hp   = hq + (size_t)g * BG * HDIM + (size_t)l16 * HDIM + wv * 64 + lk * 8;
  ull*       hdst = hq + (size_t)g * BG * HDIM + (size_t)ub * HDIM + w * 16 + uc;

  // preload x for t=0
  fl4 xa = *(const fl4*)(x + xbase);
  fl4 xb = *(const fl4*)(x + xbase + 4);

  for (int t = 0; t < T_SEQ; ++t) {
    // issue next-step x loads (latency hides under poll/MFMA)
    const int tn = (t + 1 < T_SEQ) ? t + 1 : t;
    const float* xp = x + xbase + (size_t)tn * IDIM;
    fl4 xa_n = *(const fl4*)(xp);
    fl4 xb_n = *(const fl4*)(xp + 4);

    // ih term from current x regs (independent of h_t)
    float xs[8];
    #pragma unroll
    for (int j = 0; j < 4; ++j) { xs[j] = xa[j]; xs[4 + j] = xb[j]; }
    Frag xf;
    #pragma unroll
    for (int pj = 0; pj < 4; ++pj)
      xf.u[pj] = (uint32_t)f2bf(xs[2 * pj]) | ((uint32_t)f2bf(xs[2 * pj + 1]) << 16);

    f32x4 acc[4];
    #pragma unroll
    for (int q = 0; q < 4; ++q) {
      f32x4 z = {0.f, 0.f, 0.f, 0.f};
      acc[q] = __builtin_amdgcn_mfma_f32_16x16x32_bf16(wih[q].v, xf.v, z, 0, 0, 0);
    }

    if (t > 0) {
      const ull* hpb = hp + (size_t)(t & 1) * HBUF;   // tag t lives in buffer t&1
      // ---- spin on 2 sentinel words (one per 8-word chunk) ----
      while (true) {
        ull s0 = ld_agent(hpb + 7);
        ull s1 = ld_agent(hpb + 39);
        bool ok = ((int)(s0 >> 32) == t) & ((int)(s1 >> 32) == t);
        if (__all(ok)) break;
      }
      // ---- bulk load + exact-tag verify (retry only waits for not-yet-visible
      //      stores; ping-pong guarantees tag-t cells are never overwritten
      //      while any WG can still want them) ----
      ull hb[16];
      while (true) {
        #pragma unroll
        for (int kt = 0; kt < 2; ++kt)
          #pragma unroll
          for (int j = 0; j < 8; ++j)
            hb[kt * 8 + j] = ld_agent(hpb + kt * 32 + j);
        bool ok = true;
        #pragma unroll
        for (int i = 0; i < 16; ++i) ok &= ((int)(hb[i] >> 32) == t);
        if (__all(ok)) break;
      }
      // ---- hh term: 3-term bf16 split, fp32 accumulate ----
      #pragma unroll
      for (int kt = 0; kt < 2; ++kt) {
        Frag hh, hl;
        #pragma unroll
        for (int pj = 0; pj < 4; ++pj) {
          uint32_t e0 = (uint32_t)hb[kt * 8 + 2 * pj];
          uint32_t e1 = (uint32_t)hb[kt * 8 + 2 * pj + 1];
          hh.u[pj] = __builtin_amdgcn_perm(e1, e0, 0x07060302u);  // hi halves
          hl.u[pj] = __builtin_amdgcn_perm(e1, e0, 0x05040100u);  // lo halves
        }
        #pragma unroll
        for (int q = 0; q < 4; ++q) {
          acc[q] = __builtin_amdgcn_mfma_f32_16x16x32_bf16(whi[q][kt].v, hh.v, acc[q], 0, 0, 0);
          acc[q] = __builtin_amdgcn_mfma_f32_16x16x32_bf16(whi[q][kt].v, hl.v, acc[q], 0, 0, 0);
          acc[q] = __builtin_amdgcn_mfma_f32_16x16x32_bf16(wlo[q][kt].v, hh.v, acc[q], 0, 0, 0);
        }
      }
    }

    // write K-partials: D frag = {col=l16 -> batch, row=lk*4+r -> c}
    #pragma unroll
    for (int q = 0; q < 4; ++q)
      *(f32x4*)&ldsC[t & 1][wv][q][l16][lk * 4] = acc[q];
    __syncthreads();   // single barrier per step (LDS double-buffered)

    if (tid < 256) {
      float s0 = 0.f, s1 = 0.f, s2 = 0.f, s3 = 0.f;
      #pragma unroll
      for (int v = 0; v < 8; ++v) {
        s0 += ldsC[t & 1][v][0][ub][uc];
        s1 += ldsC[t & 1][v][1][ub][uc];
        s2 += ldsC[t & 1][v][2][ub][uc];
        s3 += ldsC[t & 1][v][3][ub][uc];
      }
      float ig = sigm(s0 + bias[0]);
      float fg = sigm(s1 + bias[1]);
      float gg = tanh_(s2 + bias[2]);
      float og = sigm(s3 + bias[3]);
      cstate = fg * cstate + ig * gg;
      float hval = og * tanh_(cstate);

      unsigned short hh16 = f2bf(hval);
      unsigned short hl16 = f2bf(hval - bf2f(hh16));
      uint32_t pk = ((uint32_t)hh16 << 16) | (uint32_t)hl16;
      // publish h_{t+1} with tag t+1 into buffer (t+1)&1
      st_agent(hdst + (size_t)((t + 1) & 1) * HBUF,
               ((ull)(uint32_t)(t + 1) << 32) | (ull)pk);
    }
    xa = xa_n; xb = xb_n;
  }
}

__global__ void head_fc(const ull* __restrict__ hq,   // buffer 0 holds tag-2048 h
                        const float* __restrict__ W_fc,
                        const float* __restrict__ b_fc,
                        float* __restrict__ out)
{
  const int tid = threadIdx.x;     // 640 threads: 10 waves, wave = one output o
  const int b = tid & 63;          // [grp][16b] layout flattens to batch index b
  const int o = __builtin_amdgcn_readfirstlane(tid >> 6);
  const ull* hb_ = hq + (size_t)b * HDIM;
  float acc = 0.f;
  #pragma unroll 8
  for (int j = 0; j < HDIM; ++j) {
    uint32_t pk = (uint32_t)hb_[j];
    float h = bf2f((unsigned short)(pk >> 16)) + bf2f((unsigned short)(pk & 0xffffu));
    acc += h * W_fc[(size_t)o * HDIM + j];
  }
  out[b * ODIM + o] = acc + b_fc[o];
}

extern "C" void kernel_launch(void* const* d_in, const int* in_sizes, int n_in,
                              void* d_out, int out_size, void* d_ws, size_t ws_size,
                              hipStream_t stream)
{
  const float* x    = (const float*)d_in[0];
  const float* W_ih = (const float*)d_in[1];
  const float* W_hh = (const float*)d_in[2];
  const float* b_ih = (const float*)d_in[3];
  const float* b_hh = (const float*)d_in[4];
  const float* W_fc = (const float*)d_in[5];
  const float* b_fc = (const float*)d_in[6];
  float* out = (float*)d_out;

  // ws layout: hq[2][HBUF] u64 = 512KB total. 0xAA poison tag never matches a
  // step tag in [1,2048]; exact-match tags make the protocol replay-safe.
  ull* hq = (ull*)d_ws;

  void* args[] = { (void*)&x, (void*)&W_ih, (void*)&W_hh, (void*)&b_ih, (void*)&b_hh,
                   (void*)&hq };
  hipLaunchCooperativeKernel((const void*)lstm_persist, dim3(NWG), dim3(NTHR),
                             args, 0, stream);

  head_fc<<<dim3(1), dim3(640), 0, stream>>>(hq, W_fc, b_fc, out);
}

// Round 6
// 8594.975 us; speedup vs baseline: 2.0367x; 2.0367x over previous
//
#include <hip/hip_runtime.h>
#include <hip/hip_bf16.h>
#include <stdint.h>

// LSTM: B=64, T=2048, I=256, H=512, O=10 (fp32 in/out)
// v4: kill the uncoalesced-atomic transaction flood (v1/v3's real bottleneck).
//  - 64 WGs x 512 thr. 4 groups x 16 WGs; group g owns batches [16g,16g+16).
//  - WG w owns 32 h-cols [32w,32w+32) => gate rows q*512+32w+c. Fewer WGs x
//    wider cols halves the per-step h-broadcast (4MB/step).
//  - All h traffic via inline-asm global_load_dwordx4 / store_dwordx2 with
//    sc0 sc1 (coherent at L3, COALESCED — unlike __hip_atomic_* which issue
//    per-lane RMW transactions).
//  - Sync: per-WG flag cells (hint only, >= signed compare, poison-safe) +
//    exact-tag verify-with-retry on data (correctness gate). Ping-pong h
//    buffers: tag t lives in buf t&1; overwrite of tag-t needs all WGs at
//    t+1, i.e. all step-t reads done (proven safe in v3).
//  - Barriers: raw s_barrier + lgkmcnt(0) only — h-stores never drain vmcnt
//    on the critical path.
//  - W_hh in regs as bf16 hi/lo split A-frags (3-term fp32-accurate product);
//    W_ih single bf16.

#define T_SEQ 2048
#define NB    64
#define IDIM  256
#define HDIM  512
#define NGRP  4
#define BG    16
#define WPG   16
#define NWG   64
#define NTHR  512
#define ODIM  10
#define COLS  32
#define HBUF  (NGRP * BG * HDIM)   // u64 cells per ping-pong buffer (32768)

typedef float  f32x4  __attribute__((ext_vector_type(4)));
typedef short  short8 __attribute__((ext_vector_type(8)));
typedef float  fl4    __attribute__((ext_vector_type(4)));
typedef unsigned int uint4_ __attribute__((ext_vector_type(4)));
typedef unsigned long long ull;

union Frag { uint32_t u[4]; short8 v; };

__device__ inline unsigned short f2bf(float f) {
  unsigned int u = __float_as_uint(f);
  u += 0x7FFFu + ((u >> 16) & 1u);          // RNE
  return (unsigned short)(u >> 16);
}
__device__ inline float bf2f(unsigned short s) {
  return __uint_as_float(((unsigned int)s) << 16);
}
__device__ inline float sigm(float x)  { return 1.0f / (1.0f + __expf(-x)); }
__device__ inline float tanh_(float x) { float e = __expf(2.0f * x); return 1.0f - 2.0f / (e + 1.0f); }

__global__ __launch_bounds__(NTHR, 2)
void lstm_persist(const float* __restrict__ x,
                  const float* __restrict__ W_ih,
                  const float* __restrict__ W_hh,
                  const float* __restrict__ b_ih,
                  const float* __restrict__ b_hh,
                  ull* __restrict__ hq,     // [2][grp][16b][512c] tagged u64
                  ull* __restrict__ flg)    // [grp][16w] last-published tag
{
  __shared__ float ldsC[8][4][16][36];  // [wave][gate][batch][c(32)+pad4]

  const int bid = blockIdx.x;
  const int g   = bid & 3;           // group
  const int w   = bid >> 2;          // 0..15 within group
  const int tid = threadIdx.x;
  const int wv  = tid >> 6;          // wave 0..7
  const int l   = tid & 63;
  const int l16 = l & 15;
  const int lk  = l >> 4;            // 0..3

  // ---- one-time: W_hh bf16 hi/lo split A-frags + W_ih bf16 A-frags ----
  Frag whi[4][2][2], wlo[4][2][2], wih[4][2];
  #pragma unroll
  for (int q = 0; q < 4; ++q) {
    #pragma unroll
    for (int ct = 0; ct < 2; ++ct) {
      const int row = q * HDIM + w * COLS + ct * 16 + l16;
      #pragma unroll
      for (int kt = 0; kt < 2; ++kt) {
        const float* p = W_hh + (size_t)row * HDIM + wv * 64 + kt * 32 + lk * 8;
        #pragma unroll
        for (int pj = 0; pj < 4; ++pj) {
          float a = p[2 * pj], b2 = p[2 * pj + 1];
          unsigned short ha = f2bf(a), hb = f2bf(b2);
          unsigned short la = f2bf(a - bf2f(ha)), lb = f2bf(b2 - bf2f(hb));
          whi[q][ct][kt].u[pj] = (uint32_t)ha | ((uint32_t)hb << 16);
          wlo[q][ct][kt].u[pj] = (uint32_t)la | ((uint32_t)lb << 16);
        }
      }
      const float* pi = W_ih + (size_t)row * IDIM + wv * 32 + lk * 8;
      #pragma unroll
      for (int pj = 0; pj < 4; ++pj)
        wih[q][ct].u[pj] =
          (uint32_t)f2bf(pi[2 * pj]) | ((uint32_t)f2bf(pi[2 * pj + 1]) << 16);
    }
  }

  // ---- activation role: thread = (batch ab, col ac); c-state in register ----
  const int ab = tid >> 5;           // 0..15
  const int ac = tid & 31;           // 0..31
  float bias[4];
  #pragma unroll
  for (int q = 0; q < 4; ++q) {
    int row = q * HDIM + w * COLS + ac;
    bias[q] = b_ih[row] + b_hh[row];
  }
  float cstate = 0.0f;

  const size_t xbase = ((size_t)(g * BG + l16) * T_SEQ) * IDIM + wv * 32 + lk * 8;
  ull* hgrp = hq + (size_t)g * BG * HDIM;
  const ull* hrd = hgrp + (size_t)l16 * HDIM + wv * 64 + lk * 8;  // k-slice base
  ull*       hwr = hgrp + (size_t)ab * HDIM + w * COLS + ac;      // producer cell
  const ull* flrd = flg + g * WPG + 2 * wv;   // wave-uniform: this wave's 2 producers
  ull*       flwr = flg + g * WPG + w;

  for (int t = 0; t < T_SEQ; ++t) {
    // x_t load (plain cached) + ih term — independent of h_t, issues pre-spin
    const float* xp = x + xbase + (size_t)t * IDIM;
    fl4 xa = *(const fl4*)(xp);
    fl4 xb = *(const fl4*)(xp + 4);
    float xs[8];
    #pragma unroll
    for (int j = 0; j < 4; ++j) { xs[j] = xa[j]; xs[4 + j] = xb[j]; }
    Frag xf;
    #pragma unroll
    for (int pj = 0; pj < 4; ++pj)
      xf.u[pj] = (uint32_t)f2bf(xs[2 * pj]) | ((uint32_t)f2bf(xs[2 * pj + 1]) << 16);

    f32x4 acc[4][2];
    #pragma unroll
    for (int q = 0; q < 4; ++q)
      #pragma unroll
      for (int ct = 0; ct < 2; ++ct) {
        f32x4 z = {0.f, 0.f, 0.f, 0.f};
        acc[q][ct] = __builtin_amdgcn_mfma_f32_16x16x32_bf16(wih[q][ct].v, xf.v, z, 0, 0, 0);
      }

    if (t > 0) {
      // ---- flag-hint spin: ONE hot line per wave, uniform address ----
      {
        uint4_ f;
        while (true) {
          asm volatile("global_load_dwordx4 %0, %1, off sc0 sc1\n\t"
                       "s_waitcnt vmcnt(0)"
                       : "=&v"(f) : "v"(flrd) : "memory");
          if ((int)f.x >= t && (int)f.z >= t) break;   // hints only
        }
      }
      const ull* hb_base = hrd + (size_t)(t & 1) * HBUF;
      // ---- per-kt: coalesced 16B loads + exact-tag verify (correctness gate) ----
      #pragma unroll
      for (int kt = 0; kt < 2; ++kt) {
        const ull* p0 = hb_base + kt * 32;
        const ull* p1 = p0 + 2;
        const ull* p2 = p0 + 4;
        const ull* p3 = p0 + 6;
        uint4_ h0, h1, h2, h3;
        while (true) {
          asm volatile("global_load_dwordx4 %0, %4, off sc0 sc1\n\t"
                       "global_load_dwordx4 %1, %5, off sc0 sc1\n\t"
                       "global_load_dwordx4 %2, %6, off sc0 sc1\n\t"
                       "global_load_dwordx4 %3, %7, off sc0 sc1\n\t"
                       "s_waitcnt vmcnt(0)"
                       : "=&v"(h0), "=&v"(h1), "=&v"(h2), "=&v"(h3)
                       : "v"(p0), "v"(p1), "v"(p2), "v"(p3)
                       : "memory");
          const uint32_t tt = (uint32_t)t;
          bool ok = (h0.y == tt) & (h0.w == tt) & (h1.y == tt) & (h1.w == tt) &
                    (h2.y == tt) & (h2.w == tt) & (h3.y == tt) & (h3.w == tt);
          if (__all(ok)) break;   // retry only while stores not yet visible
        }
        // bf16 hi/lo frags from packed cells
        Frag hh, hl;
        uint32_t e0, e1;
        e0 = h0.x; e1 = h0.z;
        hh.u[0] = __builtin_amdgcn_perm(e1, e0, 0x07060302u);
        hl.u[0] = __builtin_amdgcn_perm(e1, e0, 0x05040100u);
        e0 = h1.x; e1 = h1.z;
        hh.u[1] = __builtin_amdgcn_perm(e1, e0, 0x07060302u);
        hl.u[1] = __builtin_amdgcn_perm(e1, e0, 0x05040100u);
        e0 = h2.x; e1 = h2.z;
        hh.u[2] = __builtin_amdgcn_perm(e1, e0, 0x07060302u);
        hl.u[2] = __builtin_amdgcn_perm(e1, e0, 0x05040100u);
        e0 = h3.x; e1 = h3.z;
        hh.u[3] = __builtin_amdgcn_perm(e1, e0, 0x07060302u);
        hl.u[3] = __builtin_amdgcn_perm(e1, e0, 0x05040100u);
        // 3-term split product, fp32 accumulate
        #pragma unroll
        for (int q = 0; q < 4; ++q)
          #pragma unroll
          for (int ct = 0; ct < 2; ++ct) {
            acc[q][ct] = __builtin_amdgcn_mfma_f32_16x16x32_bf16(whi[q][ct][kt].v, hh.v, acc[q][ct], 0, 0, 0);
            acc[q][ct] = __builtin_amdgcn_mfma_f32_16x16x32_bf16(whi[q][ct][kt].v, hl.v, acc[q][ct], 0, 0, 0);
            acc[q][ct] = __builtin_amdgcn_mfma_f32_16x16x32_bf16(wlo[q][ct][kt].v, hh.v, acc[q][ct], 0, 0, 0);
          }
      }
    }

    // K-partials -> LDS. D frag: col=l16 -> batch, row=lk*4+r -> c_in_tile
    #pragma unroll
    for (int q = 0; q < 4; ++q)
      #pragma unroll
      for (int ct = 0; ct < 2; ++ct)
        *(f32x4*)&ldsC[wv][q][l16][ct * 16 + lk * 4] = acc[q][ct];
    asm volatile("s_waitcnt lgkmcnt(0)\n\ts_barrier" ::: "memory");

    // reduce 8 K-partials x 4 gates; all 512 threads (one (b,c) cell each)
    float s0 = 0.f, s1 = 0.f, s2 = 0.f, s3 = 0.f;
    #pragma unroll
    for (int v = 0; v < 8; ++v) {
      s0 += ldsC[v][0][ab][ac];
      s1 += ldsC[v][1][ab][ac];
      s2 += ldsC[v][2][ab][ac];
      s3 += ldsC[v][3][ab][ac];
    }
    float ig = sigm(s0 + bias[0]);
    float fg = sigm(s1 + bias[1]);
    float gg = tanh_(s2 + bias[2]);
    float og = sigm(s3 + bias[3]);
    cstate = fg * cstate + ig * gg;
    float hval = og * tanh_(cstate);

    unsigned short hh16 = f2bf(hval);
    unsigned short hl16 = f2bf(hval - bf2f(hh16));
    uint32_t pk = ((uint32_t)hh16 << 16) | (uint32_t)hl16;
    ull hword = ((ull)(uint32_t)(t + 1) << 32) | (ull)pk;
    ull* dst = hwr + (size_t)((t + 1) & 1) * HBUF;
    asm volatile("global_store_dwordx2 %0, %1, off sc0 sc1"
                 :: "v"(dst), "v"(hword) : "memory");
    if (tid == 0) {
      ull fv = (ull)(uint32_t)(t + 1);
      asm volatile("global_store_dwordx2 %0, %1, off sc0 sc1"
                   :: "v"(flwr), "v"(fv) : "memory");
    }
    asm volatile("s_waitcnt lgkmcnt(0)\n\ts_barrier" ::: "memory");
  }
}

__global__ void head_fc(const ull* __restrict__ hq,   // buf 0 holds tag-2048 h
                        const float* __restrict__ W_fc,
                        const float* __restrict__ b_fc,
                        float* __restrict__ out)
{
  const int tid = threadIdx.x;     // 640 threads: 10 waves, wave = one output o
  const int b = tid & 63;
  const int o = __builtin_amdgcn_readfirstlane(tid >> 6);
  const ull* hb_ = hq + (size_t)b * HDIM;
  float acc = 0.f;
  #pragma unroll 8
  for (int j = 0; j < HDIM; ++j) {
    uint32_t pk = (uint32_t)hb_[j];
    float h = bf2f((unsigned short)(pk >> 16)) + bf2f((unsigned short)(pk & 0xffffu));
    acc += h * W_fc[(size_t)o * HDIM + j];
  }
  out[b * ODIM + o] = acc + b_fc[o];
}

extern "C" void kernel_launch(void* const* d_in, const int* in_sizes, int n_in,
                              void* d_out, int out_size, void* d_ws, size_t ws_size,
                              hipStream_t stream)
{
  const float* x    = (const float*)d_in[0];
  const float* W_ih = (const float*)d_in[1];
  const float* W_hh = (const float*)d_in[2];
  const float* b_ih = (const float*)d_in[3];
  const float* b_hh = (const float*)d_in[4];
  const float* W_fc = (const float*)d_in[5];
  const float* b_fc = (const float*)d_in[6];
  float* out = (float*)d_out;

  // ws: hq[2][HBUF] u64 (512KB) | flg[64] u64 (512B).
  // 0xAA poison: data tags (hi32=0xAAAAAAAA) never match t in [1,2048];
  // flag poison is negative under signed >= compare => blocks. Replay-safe.
  ull* hq  = (ull*)d_ws;
  ull* flg = (ull*)((char*)d_ws + (size_t)2 * HBUF * 8);

  void* args[] = { (void*)&x, (void*)&W_ih, (void*)&W_hh, (void*)&b_ih, (void*)&b_hh,
                   (void*)&hq, (void*)&flg };
  hipLaunchCooperativeKernel((const void*)lstm_persist, dim3(NWG), dim3(NTHR),
                             args, 0, stream);

  head_fc<<<dim3(1), dim3(640), 0, stream>>>(hq, W_fc, b_fc, out);
}